// Round 1
// baseline (444.919 us; speedup 1.0000x reference)
//
#include <hip/hip_runtime.h>

#define TWO_PI 6.283185307179586f

// B=16, L=256, hidden=32, n_bins=8, out channels = 25
// Tile: 16x16 output pixels per block, 256 threads (1 px/thread for conv2).

__global__ __launch_bounds__(256) void plaq_fused(
    const float* __restrict__ x,
    const float* __restrict__ w1, const float* __restrict__ b1,
    const float* __restrict__ w2, const float* __restrict__ b2,
    float* __restrict__ fx_out, float* __restrict__ logj_out)
{
    const int L = 256;
    const int tid = threadIdx.x;
    const int b   = blockIdx.z;
    const int gi0 = blockIdx.y * 16;
    const int gj0 = blockIdx.x * 16;

    __shared__ float xs[20][20];        // x tile with halo 2
    __shared__ float w1s[576];          // conv1 weights (O=32,I=2,3,3) flat
    __shared__ float b1s[32];
    __shared__ float hs[32][18][18];    // gelu(conv1) tile with halo 1, channel-major
    __shared__ float red[4];

    const float* xb = x + (size_t)b * L * L;

    // ---- stage x tile (circular wrap; L=256 -> &255) ----
    for (int t = tid; t < 400; t += 256) {
        int r = t / 20, c = t % 20;
        int gr = (gi0 + r - 2) & 255;
        int gc = (gj0 + c - 2) & 255;
        xs[r][c] = xb[gr * L + gc];
    }
    for (int t = tid; t < 576; t += 256) w1s[t] = w1[t];
    if (tid < 32) b1s[tid] = b1[tid];
    __syncthreads();

    // ---- conv1 (2->32, 3x3 circular) + tanh-GELU -> hs ----
    for (int p = tid; p < 324; p += 256) {
        int hi = p / 18, hj = p % 18;
        float cv[9], sv[9];
        #pragma unroll
        for (int q = 0; q < 9; q++) {
            int di = q / 3, dj = q % 3;
            int gr = gi0 + hi + di - 2;           // global row (parity only)
            int gc = gj0 + hj + dj - 2;
            int par = ((gr & 1) << 1) | (gc & 1);
            float xv = xs[hi + di][hj + dj];
            if (par == 1 || par == 2) {           // frozen site
                float sn, cs;
                sincosf(xv, &sn, &cs);
                cv[q] = cs; sv[q] = sn;
            } else {                              // p2 = 0 -> cos=1, sin=0
                cv[q] = 1.0f; sv[q] = 0.0f;
            }
        }
        for (int c = 0; c < 32; c++) {
            float a = b1s[c];
            #pragma unroll
            for (int q = 0; q < 9; q++)
                a += cv[q] * w1s[c * 18 + q] + sv[q] * w1s[c * 18 + 9 + q];
            // jax.nn.gelu default: tanh approximation
            float u = a + 0.044715f * a * a * a;
            float g = 0.5f * a * (1.0f + tanhf(0.7978845608028654f * u));
            hs[c][hi][hj] = g;
        }
    }
    __syncthreads();

    // ---- conv2 (32->25, 3x3) : one output pixel per thread ----
    const int oi = tid >> 4, oj = tid & 15;
    float acc[25];
    #pragma unroll
    for (int o = 0; o < 25; o++) acc[o] = b2[o];

    for (int c = 0; c < 32; c++) {
        float hv[9];
        #pragma unroll
        for (int q = 0; q < 9; q++)
            hv[q] = hs[c][oi + q / 3][oj + q % 3];
        #pragma unroll
        for (int o = 0; o < 25; o++) {
            const float* wp = w2 + (size_t)(o * 32 + c) * 9;  // uniform -> s_load
            float a = acc[o];
            #pragma unroll
            for (int q = 0; q < 9; q++) a += hv[q] * wp[q];
            acc[o] = a;
        }
    }

    // ---- spline / output ----
    const int gi = gi0 + oi, gj = gj0 + oj;
    const float xv = xs[oi + 2][oj + 2];
    float fx;
    float logd = 0.0f;

    if (((gi | gj) & 1) == 0) {   // active site: i even, j even
        float kx[9], ky[9], sa[9];
        // softmax over acc[0..7] -> kx knots
        {
            float mx = acc[0];
            #pragma unroll
            for (int k = 1; k < 8; k++) mx = fmaxf(mx, acc[k]);
            float ev[8]; float sum = 0.f;
            #pragma unroll
            for (int k = 0; k < 8; k++) { ev[k] = expf(acc[k] - mx); sum += ev[k]; }
            float inv = TWO_PI / sum;
            float run = 0.f;
            kx[0] = 0.f;
            #pragma unroll
            for (int k = 0; k < 8; k++) { run += ev[k]; kx[k + 1] = run * inv; }
            kx[8] = TWO_PI;
        }
        // softmax over acc[8..15] -> ky knots
        {
            float mx = acc[8];
            #pragma unroll
            for (int k = 1; k < 8; k++) mx = fmaxf(mx, acc[8 + k]);
            float ev[8]; float sum = 0.f;
            #pragma unroll
            for (int k = 0; k < 8; k++) { ev[k] = expf(acc[8 + k] - mx); sum += ev[k]; }
            float inv = TWO_PI / sum;
            float run = 0.f;
            ky[0] = 0.f;
            #pragma unroll
            for (int k = 0; k < 8; k++) { run += ev[k]; ky[k + 1] = run * inv; }
            ky[8] = TWO_PI;
        }
        // softplus over acc[16..23] -> derivatives
        #pragma unroll
        for (int k = 0; k < 8; k++) {
            float v = acc[16 + k];
            sa[k] = (v > 20.f) ? v : log1pf(expf(v));
        }
        sa[8] = sa[0];

        float x1 = fmodf(xv, TWO_PI);
        if (x1 < 0.f) x1 += TWO_PI;

        int idx = 0;
        #pragma unroll
        for (int k = 1; k < 8; k++) idx += (kx[k] <= x1) ? 1 : 0;

        // select knots with constant indices (keep arrays in registers)
        float xk = 0, xk1 = 0, yk = 0, yk1 = 0, dk = 0, dk1 = 0;
        #pragma unroll
        for (int k = 0; k < 9; k++) {
            if (k == idx)     { xk  = kx[k]; yk  = ky[k]; dk  = sa[k]; }
            if (k == idx + 1) { xk1 = kx[k]; yk1 = ky[k]; dk1 = sa[k]; }
        }

        float wk  = xk1 - xk;
        float hk  = yk1 - yk;
        float sl  = hk / wk;
        float th  = (x1 - xk) / wk;
        float th1 = th * (1.f - th);
        float den = sl + (dk1 + dk - 2.f * sl) * th1;
        float fx1 = yk + hk * (sl * th * th + dk * th1) / den;
        float omt = 1.f - th;
        float deriv = sl * sl * (dk1 * th * th + 2.f * sl * th1 + dk * omt * omt)
                      / (den * den);
        logd = logf(deriv);

        float t = acc[24];
        float m = fmodf(fx1 + t, TWO_PI);
        if (m < 0.f) m += TWO_PI;
        fx = m;
    } else {
        fx = xv;   // passive + frozen both pass x through
    }

    fx_out[(size_t)b * L * L + gi * L + gj] = fx;

    // ---- logJ block reduction -> atomicAdd ----
    #pragma unroll
    for (int off = 32; off > 0; off >>= 1)
        logd += __shfl_down(logd, off);
    if ((tid & 63) == 0) red[tid >> 6] = logd;
    __syncthreads();
    if (tid == 0) atomicAdd(&logj_out[b], red[0] + red[1] + red[2] + red[3]);
}

extern "C" void kernel_launch(void* const* d_in, const int* in_sizes, int n_in,
                              void* d_out, int out_size, void* d_ws, size_t ws_size,
                              hipStream_t stream) {
    const float* x  = (const float*)d_in[0];
    // d_in[1..3] = active/frozen/passive masks — derived from parity instead
    const float* w1 = (const float*)d_in[4];
    const float* b1 = (const float*)d_in[5];
    const float* w2 = (const float*)d_in[6];
    const float* b2 = (const float*)d_in[7];

    float* fx_out = (float*)d_out;
    float* logj   = (float*)d_out + (size_t)16 * 256 * 256;

    hipMemsetAsync(logj, 0, 16 * sizeof(float), stream);

    dim3 grid(16, 16, 16);   // (j-tiles, i-tiles, batch)
    plaq_fused<<<grid, 256, 0, stream>>>(x, w1, b1, w2, b2, fx_out, logj);
}

// Round 2
// 135.487 us; speedup vs baseline: 3.2838x; 3.2838x over previous
//
#include <hip/hip_runtime.h>
#include <hip/hip_bf16.h>

#define TWO_PI 6.283185307179586f

typedef __attribute__((ext_vector_type(8))) short short8;
typedef __attribute__((ext_vector_type(4))) float f32x4;

__device__ __forceinline__ unsigned pack2_bf16(float lo, float hi) {
    unsigned a = __float_as_uint(lo), b = __float_as_uint(hi);
    a = (a + 0x7fffu + ((a >> 16) & 1)) >> 16;          // RNE to bf16
    b = (b + 0x7fffu + ((b >> 16) & 1)) & 0xffff0000u;
    return b | a;
}
__device__ __forceinline__ unsigned short f2bf16(float f) {
    unsigned a = __float_as_uint(f);
    return (unsigned short)((a + 0x7fffu + ((a >> 16) & 1)) >> 16);
}
__device__ __forceinline__ float bf162f(unsigned short h) {
    return __uint_as_float(((unsigned)h) << 16);
}
__device__ __forceinline__ float gelu_fast(float a) {
    // jax tanh-gelu: a*sigmoid(1.595769122*(a+0.044715 a^3))
    float u = a + 0.044715f * a * a * a;
    float e = __expf(-1.5957691216057308f * u);
    return a * __builtin_amdgcn_rcpf(1.0f + e);
}

// B=16, L=256, hidden=32, n_bins=8, n_out=25. Tile 16x16, 256 threads (4 waves).
__global__ __launch_bounds__(256, 3) void plaq_fused(
    const float* __restrict__ x,
    const float* __restrict__ w1, const float* __restrict__ b1,
    const float* __restrict__ w2, const float* __restrict__ b2,
    float* __restrict__ fx_out, float* __restrict__ logj_out)
{
    const int L = 256;
    const int tid = threadIdx.x;
    const int bb  = blockIdx.z;
    const int gi0 = blockIdx.y * 16;
    const int gj0 = blockIdx.x * 16;

    __shared__ float xs[20][20];                        // x tile, halo 2 (1600 B)
    __shared__ union {
        unsigned cssn[400];                             // packed bf16 (cos,sin), dead after conv1
        unsigned short net_out[256 * 26];               // conv2 out, bf16, stride 26
    } sm;                                               // 13312 B
    __shared__ __align__(16) unsigned short hs[4][18][18][8];  // gelu(conv1), bf16, c-blocked (20736 B)
    __shared__ __align__(16) unsigned short wt[9][4][32][8];   // conv2 weights bf16 [q][cb][o][ci] (18432 B)
    __shared__ float red[4];

    const float* xb = x + (size_t)bb * L * L;

    // ---- phase 0: stage x tile + packed cos/sin (frozen parity only) ----
    for (int t = tid; t < 400; t += 256) {
        int r = t / 20, c = t % 20;
        int gr = (gi0 + r - 2) & 255;
        int gc = (gj0 + c - 2) & 255;
        float v = xb[gr * L + gc];
        xs[r][c] = v;
        float cs, sn;
        if ((gr ^ gc) & 1) { __sincosf(v, &sn, &cs); }   // frozen site
        else               { cs = 1.0f; sn = 0.0f; }     // p2 = 0
        sm.cssn[t] = pack2_bf16(cs, sn);
    }
    __syncthreads();

    // ---- phase 1a: stage conv2 weights transposed -> wt[q][cb][o][ci] (bf16) ----
    for (int idx = tid; idx < 9216; idx += 256) {
        int q  = idx >> 10;
        int r  = idx & 1023;
        int cb = r >> 8;
        int o  = (r >> 3) & 31;
        int ci = r & 7;
        int c  = cb * 8 + ci;
        float v = (o < 25) ? w2[(o * 32 + c) * 9 + q] : 0.0f;
        wt[q][cb][o][ci] = f2bf16(v);
    }

    // ---- phase 1b: conv1 (2->32) + GELU -> hs (bf16). thread = (pos-group, ch-pair) ----
    {
        const int cp = tid & 15;      // channel pair 0..15 -> c0 = 2*cp
        const int g  = tid >> 4;      // position group 0..15
        const int c0 = cp * 2;
        float wr[36];
        #pragma unroll
        for (int i = 0; i < 18; ++i) wr[i]      = w1[c0 * 18 + i];
        #pragma unroll
        for (int i = 0; i < 18; ++i) wr[18 + i] = w1[(c0 + 1) * 18 + i];
        const float bias0 = b1[c0], bias1 = b1[c0 + 1];

        int hi = 0, hj = g;
        for (int p = g; p < 324; p += 16) {
            float cv[9], sv[9];
            #pragma unroll
            for (int dq = 0; dq < 9; ++dq) {
                unsigned uu = sm.cssn[(hi + dq / 3) * 20 + (hj + dq % 3)];
                cv[dq] = __uint_as_float(uu << 16);
                sv[dq] = __uint_as_float(uu & 0xffff0000u);
            }
            float a0 = bias0, a1 = bias1;
            #pragma unroll
            for (int dq = 0; dq < 9; ++dq) {
                a0 += cv[dq] * wr[dq]      + sv[dq] * wr[9 + dq];
                a1 += cv[dq] * wr[18 + dq] + sv[dq] * wr[27 + dq];
            }
            *(unsigned*)&hs[cp >> 2][hi][hj][c0 & 7] = pack2_bf16(gelu_fast(a0), gelu_fast(a1));
            hj += 16; if (hj >= 18) { hj -= 18; ++hi; }
        }
    }
    __syncthreads();

    // ---- phase 2: conv2 via MFMA (implicit GEMM, K-step = one 3x3 tap) ----
    {
        const int w  = tid >> 6;      // wave -> rows 4w..4w+3
        const int l  = tid & 63;
        const int lg = l >> 4;        // k-slice group (c = 8*lg + i)
        const int lr = l & 15;        // A row (=oj) / B col (=o)

        float bv0 = b2[lr];
        float bv1 = (lr < 9) ? b2[16 + lr] : 0.0f;
        f32x4 acc[4][2];
        #pragma unroll
        for (int mt = 0; mt < 4; ++mt) {
            acc[mt][0] = (f32x4){bv0, bv0, bv0, bv0};
            acc[mt][1] = (f32x4){bv1, bv1, bv1, bv1};
        }

        #pragma unroll
        for (int q = 0; q < 9; ++q) {
            const int di = q / 3, dj = q % 3;
            short8 bf0 = *(const short8*)&wt[q][lg][lr][0];
            short8 bf1 = *(const short8*)&wt[q][lg][16 + lr][0];
            #pragma unroll
            for (int mt = 0; mt < 4; ++mt) {
                const int oi = w * 4 + mt;
                short8 af = *(const short8*)&hs[lg][oi + di][lr + dj][0];
                acc[mt][0] = __builtin_amdgcn_mfma_f32_16x16x32_bf16(af, bf0, acc[mt][0], 0, 0, 0);
                acc[mt][1] = __builtin_amdgcn_mfma_f32_16x16x32_bf16(af, bf1, acc[mt][1], 0, 0, 0);
            }
        }

        // scatter to net_out (bf16): lane holds o=lr(+16), oj=4*lg+r, oi=4w+mt
        #pragma unroll
        for (int mt = 0; mt < 4; ++mt) {
            #pragma unroll
            for (int r = 0; r < 4; ++r) {
                int p = (w * 4 + mt) * 16 + (lg * 4 + r);
                sm.net_out[p * 26 + lr] = f2bf16(acc[mt][0][r]);
                if (lr < 9) sm.net_out[p * 26 + 16 + lr] = f2bf16(acc[mt][1][r]);
            }
        }
    }
    __syncthreads();

    // ---- phase 3: spline / output, thread = pixel ----
    const int oi = tid >> 4, oj = tid & 15;
    const int gi = gi0 + oi, gj = gj0 + oj;
    const float xv = xs[oi + 2][oj + 2];
    float fx;
    float logd = 0.0f;

    if (((gi | gj) & 1) == 0) {   // active: both even
        float no[25];
        #pragma unroll
        for (int ch = 0; ch < 25; ++ch) no[ch] = bf162f(sm.net_out[tid * 26 + ch]);

        float kx[9], ky[9], sa[9];
        {
            float mx = no[0];
            #pragma unroll
            for (int k = 1; k < 8; ++k) mx = fmaxf(mx, no[k]);
            float ev[8]; float sum = 0.f;
            #pragma unroll
            for (int k = 0; k < 8; ++k) { ev[k] = __expf(no[k] - mx); sum += ev[k]; }
            float inv = TWO_PI / sum;
            float run = 0.f;
            kx[0] = 0.f;
            #pragma unroll
            for (int k = 0; k < 8; ++k) { run += ev[k]; kx[k + 1] = run * inv; }
            kx[8] = TWO_PI;
        }
        {
            float mx = no[8];
            #pragma unroll
            for (int k = 1; k < 8; ++k) mx = fmaxf(mx, no[8 + k]);
            float ev[8]; float sum = 0.f;
            #pragma unroll
            for (int k = 0; k < 8; ++k) { ev[k] = __expf(no[8 + k] - mx); sum += ev[k]; }
            float inv = TWO_PI / sum;
            float run = 0.f;
            ky[0] = 0.f;
            #pragma unroll
            for (int k = 0; k < 8; ++k) { run += ev[k]; ky[k + 1] = run * inv; }
            ky[8] = TWO_PI;
        }
        #pragma unroll
        for (int k = 0; k < 8; ++k) {
            float v = no[16 + k];
            sa[k] = (v > 20.f) ? v : __logf(1.0f + __expf(v));
        }
        sa[8] = sa[0];

        float x1 = fmodf(xv, TWO_PI);
        if (x1 < 0.f) x1 += TWO_PI;

        int idx = 0;
        #pragma unroll
        for (int k = 1; k < 8; ++k) idx += (kx[k] <= x1) ? 1 : 0;

        float xk = 0, xk1 = 0, yk = 0, yk1 = 0, dk = 0, dk1 = 0;
        #pragma unroll
        for (int k = 0; k < 9; ++k) {
            if (k == idx)     { xk  = kx[k]; yk  = ky[k]; dk  = sa[k]; }
            if (k == idx + 1) { xk1 = kx[k]; yk1 = ky[k]; dk1 = sa[k]; }
        }

        float wk  = xk1 - xk;
        float hk  = yk1 - yk;
        float sl  = hk / wk;
        float th  = (x1 - xk) / wk;
        float th1 = th * (1.f - th);
        float den = sl + (dk1 + dk - 2.f * sl) * th1;
        float fx1 = yk + hk * (sl * th * th + dk * th1) / den;
        float omt = 1.f - th;
        float deriv = sl * sl * (dk1 * th * th + 2.f * sl * th1 + dk * omt * omt)
                      / (den * den);
        logd = __logf(deriv);

        float t = no[24];
        float m = fmodf(fx1 + t, TWO_PI);
        if (m < 0.f) m += TWO_PI;
        fx = m;
    } else {
        fx = xv;   // passive + frozen pass-through
    }

    fx_out[(size_t)bb * L * L + gi * L + gj] = fx;

    // ---- logJ block reduction -> atomicAdd ----
    #pragma unroll
    for (int off = 32; off > 0; off >>= 1)
        logd += __shfl_down(logd, off);
    if ((tid & 63) == 0) red[tid >> 6] = logd;
    __syncthreads();
    if (tid == 0) atomicAdd(&logj_out[bb], red[0] + red[1] + red[2] + red[3]);
}

extern "C" void kernel_launch(void* const* d_in, const int* in_sizes, int n_in,
                              void* d_out, int out_size, void* d_ws, size_t ws_size,
                              hipStream_t stream) {
    const float* x  = (const float*)d_in[0];
    const float* w1 = (const float*)d_in[4];
    const float* b1 = (const float*)d_in[5];
    const float* w2 = (const float*)d_in[6];
    const float* b2 = (const float*)d_in[7];

    float* fx_out = (float*)d_out;
    float* logj   = (float*)d_out + (size_t)16 * 256 * 256;

    hipMemsetAsync(logj, 0, 16 * sizeof(float), stream);

    dim3 grid(16, 16, 16);   // (j-tiles, i-tiles, batch)
    plaq_fused<<<grid, 256, 0, stream>>>(x, w1, b1, w2, b2, fx_out, logj);
}

// Round 3
// 86.440 us; speedup vs baseline: 5.1471x; 1.5674x over previous
//
#include <hip/hip_runtime.h>
#include <hip/hip_bf16.h>

#define TWO_PI 6.283185307179586f

typedef __attribute__((ext_vector_type(8))) short short8;
typedef __attribute__((ext_vector_type(4))) float f32x4;

__device__ __forceinline__ unsigned pack2_bf16(float lo, float hi) {
    unsigned a = __float_as_uint(lo), b = __float_as_uint(hi);
    a = (a + 0x7fffu + ((a >> 16) & 1)) >> 16;          // RNE
    b = (b + 0x7fffu + ((b >> 16) & 1)) & 0xffff0000u;
    return b | a;
}
__device__ __forceinline__ unsigned short f2bf16(float f) {
    unsigned a = __float_as_uint(f);
    return (unsigned short)((a + 0x7fffu + ((a >> 16) & 1)) >> 16);
}
__device__ __forceinline__ float gelu_fast(float a) {
    // jax tanh-gelu == a * sigmoid(1.5957691*(a + 0.044715 a^3))
    float u = a + 0.044715f * a * a * a;
    float e = __expf(-1.5957691216057308f * u);
    return a * __builtin_amdgcn_rcpf(1.0f + e);
}

// ---- weight prep: runs once per launch, writes bf16 weights to d_ws ----
// ws[0..1024)      : w1t[32 o][32 k], k = 2*tap + in  (k>=18 zero)
// ws[1024..10240)  : wt[9 q][4 cb][32 o][8 ci]        (o>=25 zero)
__global__ void prep_weights(const float* __restrict__ w1,
                             const float* __restrict__ w2,
                             unsigned short* __restrict__ ws) {
    for (int t = threadIdx.x; t < 10240; t += 256) {
        float f = 0.0f;
        if (t < 1024) {
            int o = t >> 5, k = t & 31;
            if (k < 18) f = w1[o * 18 + (k & 1) * 9 + (k >> 1)];
        } else {
            int idx = t - 1024;
            int q  = idx >> 10;
            int r  = idx & 1023;
            int cb = r >> 8;
            int o  = (r >> 3) & 31;
            int ci = r & 7;
            if (o < 25) f = w2[(o * 32 + cb * 8 + ci) * 9 + q];
        }
        ws[t] = f2bf16(f);
    }
}

// B=16, L=256, hidden=32, n_bins=8, n_out=25. Tile 16x16, 256 threads (4 waves).
__global__ __launch_bounds__(256, 3) void plaq_fused(
    const float* __restrict__ x,
    const float* __restrict__ b1, const float* __restrict__ b2,
    const unsigned short* __restrict__ ws,
    float* __restrict__ fx_out, float* __restrict__ logj_out)
{
    const int tid = threadIdx.x;
    const int bb  = blockIdx.z;
    const int gi0 = blockIdx.y * 16;
    const int gj0 = blockIdx.x * 16;

    __shared__ float xs[20][20];                          // 1600 B
    __shared__ __align__(16) union {
        unsigned a_u32[336][20];   // conv1 im2col A, bf16 pairs; taps 0..8 data,
                                   // 9..15 zero (k=18..31), 16..19 pad (26880 B)
        float net_out[256 * 27];   // conv2 out f32, stride 27 (27648 B)
    } sm;
    __shared__ __align__(16) unsigned short hs[4][18][18][8]; // gelu(conv1) bf16 (20736 B)
    __shared__ float red[4];

    const float* xb = x + (size_t)bb * 65536;

    // ---- P0: stage x, compute cos/sin, scatter into im2col A ----
    for (int t = tid; t < 2352; t += 256) sm.a_u32[t / 7][9 + t % 7] = 0;
    for (int t = tid; t < 400; t += 256) {
        int r = t / 20, c = t % 20;
        int gr = (gi0 + r - 2) & 255, gc = (gj0 + c - 2) & 255;
        float v = xb[gr * 256 + gc];
        xs[r][c] = v;
        unsigned pk;
        if ((gr ^ gc) & 1) { float sn, cs; __sincosf(v, &sn, &cs); pk = pack2_bf16(cs, sn); }
        else               { pk = 0x3f80u; }   // (cos,sin)=(1,0)
        #pragma unroll
        for (int di = 0; di < 3; ++di) {
            #pragma unroll
            for (int dj = 0; dj < 3; ++dj) {
                int pi = r - di, pj = c - dj;
                if (pi >= 0 && pi < 18 && pj >= 0 && pj < 18)
                    sm.a_u32[pi * 18 + pj][di * 3 + dj] = pk;
            }
        }
    }
    __syncthreads();

    const int w  = tid >> 6;
    const int l  = tid & 63;
    const int lg = l >> 4;        // k-slice group
    const int lr = l & 15;        // A-row / B-col within tile

    // ---- P1: conv1 via MFMA (M=324 pos, N=32 ch, K=18->32) + GELU -> hs ----
    {
        short8 bf0 = *(const short8*)(ws + (lr * 32 + lg * 8));
        short8 bf1 = *(const short8*)(ws + ((16 + lr) * 32 + lg * 8));
        float bias0 = b1[lr], bias1 = b1[16 + lr];
        for (int mt = w; mt < 21; mt += 4) {
            short8 af = *(const short8*)&sm.a_u32[mt * 16 + lr][lg * 4];
            f32x4 d0 = (f32x4){0, 0, 0, 0}, d1 = (f32x4){0, 0, 0, 0};
            d0 = __builtin_amdgcn_mfma_f32_16x16x32_bf16(af, bf0, d0, 0, 0, 0);
            d1 = __builtin_amdgcn_mfma_f32_16x16x32_bf16(af, bf1, d1, 0, 0, 0);
            int cb0 = lr >> 3, ci0 = lr & 7;          // c = lr
            int cb1 = (16 + lr) >> 3, ci1 = lr & 7;   // c = 16+lr
            #pragma unroll
            for (int r = 0; r < 4; ++r) {
                int p = mt * 16 + lg * 4 + r;
                if (p < 324) {
                    int hi = p / 18, hj = p - hi * 18;
                    hs[cb0][hi][hj][ci0] = f2bf16(gelu_fast(d0[r] + bias0));
                    hs[cb1][hi][hj][ci1] = f2bf16(gelu_fast(d1[r] + bias1));
                }
            }
        }
    }
    __syncthreads();

    // ---- P2: conv2 via MFMA (implicit GEMM, K-step = one 3x3 tap) ----
    {
        const unsigned short* wt = ws + 1024;   // [9][4][32][8]
        float bv0 = b2[lr];
        float bv1 = (lr < 9) ? b2[16 + lr] : 0.0f;
        f32x4 acc[4][2];
        #pragma unroll
        for (int mt = 0; mt < 4; ++mt) {
            acc[mt][0] = (f32x4){bv0, bv0, bv0, bv0};
            acc[mt][1] = (f32x4){bv1, bv1, bv1, bv1};
        }
        for (int di = 0; di < 3; ++di) {          // not unrolled: bounds VGPRs
            #pragma unroll
            for (int dj = 0; dj < 3; ++dj) {
                int q = di * 3 + dj;
                short8 bf0 = *(const short8*)(wt + ((q * 4 + lg) * 32 + lr) * 8);
                short8 bf1 = *(const short8*)(wt + ((q * 4 + lg) * 32 + 16 + lr) * 8);
                #pragma unroll
                for (int mt = 0; mt < 4; ++mt) {
                    short8 af = *(const short8*)&hs[lg][w * 4 + mt + di][lr + dj][0];
                    acc[mt][0] = __builtin_amdgcn_mfma_f32_16x16x32_bf16(af, bf0, acc[mt][0], 0, 0, 0);
                    acc[mt][1] = __builtin_amdgcn_mfma_f32_16x16x32_bf16(af, bf1, acc[mt][1], 0, 0, 0);
                }
            }
        }
        #pragma unroll
        for (int mt = 0; mt < 4; ++mt) {
            #pragma unroll
            for (int r = 0; r < 4; ++r) {
                int p = (w * 4 + mt) * 16 + (lg * 4 + r);
                sm.net_out[p * 27 + lr] = acc[mt][0][r];
                if (lr < 9) sm.net_out[p * 27 + 16 + lr] = acc[mt][1][r];
            }
        }
    }
    __syncthreads();

    // ---- P3: spline / output, thread = pixel ----
    const int oi = tid >> 4, oj = tid & 15;
    const int gi = gi0 + oi, gj = gj0 + oj;
    const float xv = xs[oi + 2][oj + 2];
    float fx;
    float logd = 0.0f;

    if (((gi | gj) & 1) == 0) {   // active: both even
        float no[25];
        #pragma unroll
        for (int ch = 0; ch < 25; ++ch) no[ch] = sm.net_out[tid * 27 + ch];

        float kx[9], ky[9], sa[9];
        {
            float mx = no[0];
            #pragma unroll
            for (int k = 1; k < 8; ++k) mx = fmaxf(mx, no[k]);
            float ev[8]; float sum = 0.f;
            #pragma unroll
            for (int k = 0; k < 8; ++k) { ev[k] = __expf(no[k] - mx); sum += ev[k]; }
            float inv = TWO_PI / sum;
            float run = 0.f;
            kx[0] = 0.f;
            #pragma unroll
            for (int k = 0; k < 8; ++k) { run += ev[k]; kx[k + 1] = run * inv; }
            kx[8] = TWO_PI;
        }
        {
            float mx = no[8];
            #pragma unroll
            for (int k = 1; k < 8; ++k) mx = fmaxf(mx, no[8 + k]);
            float ev[8]; float sum = 0.f;
            #pragma unroll
            for (int k = 0; k < 8; ++k) { ev[k] = __expf(no[8 + k] - mx); sum += ev[k]; }
            float inv = TWO_PI / sum;
            float run = 0.f;
            ky[0] = 0.f;
            #pragma unroll
            for (int k = 0; k < 8; ++k) { run += ev[k]; ky[k + 1] = run * inv; }
            ky[8] = TWO_PI;
        }
        #pragma unroll
        for (int k = 0; k < 8; ++k) {
            float v = no[16 + k];
            sa[k] = (v > 20.f) ? v : __logf(1.0f + __expf(v));
        }
        sa[8] = sa[0];

        float x1 = fmodf(xv, TWO_PI);
        if (x1 < 0.f) x1 += TWO_PI;

        int idx = 0;
        #pragma unroll
        for (int k = 1; k < 8; ++k) idx += (kx[k] <= x1) ? 1 : 0;

        float xk = 0, xk1 = 0, yk = 0, yk1 = 0, dk = 0, dk1 = 0;
        #pragma unroll
        for (int k = 0; k < 9; ++k) {
            if (k == idx)     { xk  = kx[k]; yk  = ky[k]; dk  = sa[k]; }
            if (k == idx + 1) { xk1 = kx[k]; yk1 = ky[k]; dk1 = sa[k]; }
        }

        float wk  = xk1 - xk;
        float hk  = yk1 - yk;
        float sl  = hk / wk;
        float th  = (x1 - xk) / wk;
        float th1 = th * (1.f - th);
        float den = sl + (dk1 + dk - 2.f * sl) * th1;
        float fx1 = yk + hk * (sl * th * th + dk * th1) / den;
        float omt = 1.f - th;
        float deriv = sl * sl * (dk1 * th * th + 2.f * sl * th1 + dk * omt * omt)
                      / (den * den);
        logd = __logf(deriv);

        float t = no[24];
        float m = fmodf(fx1 + t, TWO_PI);
        if (m < 0.f) m += TWO_PI;
        fx = m;
    } else {
        fx = xv;   // passive + frozen pass-through
    }

    fx_out[(size_t)bb * 65536 + gi * 256 + gj] = fx;

    // ---- logJ reduction ----
    #pragma unroll
    for (int off = 32; off > 0; off >>= 1)
        logd += __shfl_down(logd, off);
    if ((tid & 63) == 0) red[tid >> 6] = logd;
    __syncthreads();
    if (tid == 0) atomicAdd(&logj_out[bb], red[0] + red[1] + red[2] + red[3]);
}

extern "C" void kernel_launch(void* const* d_in, const int* in_sizes, int n_in,
                              void* d_out, int out_size, void* d_ws, size_t ws_size,
                              hipStream_t stream) {
    const float* x  = (const float*)d_in[0];
    const float* w1 = (const float*)d_in[4];
    const float* b1 = (const float*)d_in[5];
    const float* w2 = (const float*)d_in[6];
    const float* b2 = (const float*)d_in[7];

    float* fx_out = (float*)d_out;
    float* logj   = (float*)d_out + (size_t)16 * 256 * 256;
    unsigned short* ws = (unsigned short*)d_ws;

    hipMemsetAsync(logj, 0, 16 * sizeof(float), stream);
    prep_weights<<<1, 256, 0, stream>>>(w1, w2, ws);

    dim3 grid(16, 16, 16);   // (j-tiles, i-tiles, batch)
    plaq_fused<<<grid, 256, 0, stream>>>(x, b1, b2, ws, fx_out, logj);
}

// Round 4
// 82.541 us; speedup vs baseline: 5.3903x; 1.0472x over previous
//
#include <hip/hip_runtime.h>
#include <hip/hip_bf16.h>

#define TWO_PI 6.283185307179586f

typedef __attribute__((ext_vector_type(8))) short short8;
typedef __attribute__((ext_vector_type(4))) float f32x4;
typedef __attribute__((ext_vector_type(4))) unsigned u32x4;

__device__ __forceinline__ unsigned pack2_bf16(float lo, float hi) {
    unsigned a = __float_as_uint(lo), b = __float_as_uint(hi);
    a = (a + 0x7fffu + ((a >> 16) & 1)) >> 16;          // RNE
    b = (b + 0x7fffu + ((b >> 16) & 1)) & 0xffff0000u;
    return b | a;
}
__device__ __forceinline__ unsigned short f2bf16(float f) {
    unsigned a = __float_as_uint(f);
    return (unsigned short)((a + 0x7fffu + ((a >> 16) & 1)) >> 16);
}
__device__ __forceinline__ float bf162f(unsigned short h) {
    return __uint_as_float(((unsigned)h) << 16);
}
__device__ __forceinline__ float gelu_fast(float a) {
    // jax tanh-gelu == a * sigmoid(1.5957691*(a + 0.044715 a^3))
    float u = a + 0.044715f * a * a * a;
    float e = __expf(-1.5957691216057308f * u);
    return a * __builtin_amdgcn_rcpf(1.0f + e);
}

// ---- weight prep: once per launch -> d_ws (bf16) ----
// ws[0..1024)      : w1t[32 o][32 k], k = 2*tap + in  (k>=18 zero)
// ws[1024..10240)  : wt[9 q][4 cb][32 o][8 ci]        (o>=25 zero)
__global__ void prep_weights(const float* __restrict__ w1,
                             const float* __restrict__ w2,
                             unsigned short* __restrict__ ws) {
    for (int t = threadIdx.x; t < 10240; t += 256) {
        float f = 0.0f;
        if (t < 1024) {
            int o = t >> 5, k = t & 31;
            if (k < 18) f = w1[o * 18 + (k & 1) * 9 + (k >> 1)];
        } else {
            int idx = t - 1024;
            int q  = idx >> 10;
            int r  = idx & 1023;
            int cb = r >> 8;
            int o  = (r >> 3) & 31;
            int ci = r & 7;
            if (o < 25) f = w2[(o * 32 + cb * 8 + ci) * 9 + q];
        }
        ws[t] = f2bf16(f);
    }
}

// B=16, L=256, hidden=32, n_bins=8, n_out=25. Tile 16x16, 256 threads (4 waves).
__global__ __launch_bounds__(256, 4) void plaq_fused(
    const float* __restrict__ x,
    const float* __restrict__ b1, const float* __restrict__ b2,
    const unsigned short* __restrict__ ws,
    float* __restrict__ fx_out, float* __restrict__ logj_out)
{
    const int tid = threadIdx.x;
    const int bb  = blockIdx.z;
    const int gi0 = blockIdx.y * 16;
    const int gj0 = blockIdx.x * 16;

    __shared__ float xs[20][20];                         // 1600 B
    __shared__ __align__(16) union {
        unsigned cssn[401];            // packed (cos,sin) bf16; [400] = zero word
        unsigned short net_out[256 * 27];  // conv2 out bf16, stride 27 (13824 B)
    } sm;
    __shared__ __align__(16) unsigned short hs[4][18][18][8]; // gelu(conv1) (20736 B)

    const float* xb = x + (size_t)bb * 65536;

    // ---- P0: stage x tile + packed cos/sin ----
    for (int t = tid; t < 400; t += 256) {
        int r = t / 20, c = t % 20;
        int gr = (gi0 + r - 2) & 255, gc = (gj0 + c - 2) & 255;
        float v = xb[gr * 256 + gc];
        xs[r][c] = v;
        unsigned pk;
        if ((gr ^ gc) & 1) { float sn, cs; __sincosf(v, &sn, &cs); pk = pack2_bf16(cs, sn); }
        else               { pk = 0x3f80u; }   // (cos,sin)=(1,0)
        sm.cssn[t] = pk;
    }
    if (tid == 0) sm.cssn[400] = 0;
    __syncthreads();

    const int w  = tid >> 6;
    const int l  = tid & 63;
    const int lg = l >> 4;        // k-slice group
    const int lr = l & 15;        // A-row / B-col within 16x16 tile

    // ---- P1: conv1 via MFMA (M=324, N=32, K=18 in K=32 slot) + GELU -> hs ----
    {
        short8 bf0 = *(const short8*)(ws + (lr * 32 + lg * 8));
        short8 bf1 = *(const short8*)(ws + ((16 + lr) * 32 + lg * 8));
        float bias0 = b1[lr], bias1 = b1[16 + lr];

        // per-lane tap offsets (taps 4lg .. 4lg+3; tap>8 -> zero word @400)
        int offv[4]; bool valv[4];
        #pragma unroll
        for (int i = 0; i < 4; ++i) {
            int tap = lg * 4 + i;
            valv[i] = (tap <= 8);
            int di = tap / 3, dj = tap - di * 3;
            offv[i] = di * 20 + dj;
        }

        for (int mt = w; mt < 21; mt += 4) {
            int p  = mt * 16 + lr;
            int hi = p / 18, hj = p - hi * 18;
            int base = hi * 20 + hj;
            u32x4 aw;
            #pragma unroll
            for (int i = 0; i < 4; ++i)
                aw[i] = sm.cssn[valv[i] ? base + offv[i] : 400];
            short8 af = __builtin_bit_cast(short8, aw);

            f32x4 d0 = (f32x4){0, 0, 0, 0}, d1 = (f32x4){0, 0, 0, 0};
            d0 = __builtin_amdgcn_mfma_f32_16x16x32_bf16(af, bf0, d0, 0, 0, 0);
            d1 = __builtin_amdgcn_mfma_f32_16x16x32_bf16(af, bf1, d1, 0, 0, 0);

            int cb0 = lr >> 3, ci = lr & 7;
            int cb1 = 2 + (lr >> 3);
            #pragma unroll
            for (int r = 0; r < 4; ++r) {
                int pp = mt * 16 + lg * 4 + r;
                if (pp < 324) {
                    int phi = pp / 18, phj = pp - phi * 18;
                    hs[cb0][phi][phj][ci] = f2bf16(gelu_fast(d0[r] + bias0));
                    hs[cb1][phi][phj][ci] = f2bf16(gelu_fast(d1[r] + bias1));
                }
            }
        }
    }
    __syncthreads();

    // ---- P2: conv2 via MFMA (implicit GEMM, K-step = one tap) ----
    {
        const unsigned short* wt = ws + 1024;   // [9][4][32][8]
        float bv0 = b2[lr];
        float bv1 = (lr < 9) ? b2[16 + lr] : 0.0f;
        f32x4 acc[4][2];
        #pragma unroll
        for (int mt = 0; mt < 4; ++mt) {
            acc[mt][0] = (f32x4){bv0, bv0, bv0, bv0};
            acc[mt][1] = (f32x4){bv1, bv1, bv1, bv1};
        }
        for (int di = 0; di < 3; ++di) {          // outer not unrolled: bounds VGPRs
            #pragma unroll
            for (int dj = 0; dj < 3; ++dj) {
                int q = di * 3 + dj;
                short8 bf0 = *(const short8*)(wt + ((q * 4 + lg) * 32 + lr) * 8);
                short8 bf1 = *(const short8*)(wt + ((q * 4 + lg) * 32 + 16 + lr) * 8);
                #pragma unroll
                for (int mt = 0; mt < 4; ++mt) {
                    short8 af = *(const short8*)&hs[lg][w * 4 + mt + di][lr + dj][0];
                    acc[mt][0] = __builtin_amdgcn_mfma_f32_16x16x32_bf16(af, bf0, acc[mt][0], 0, 0, 0);
                    acc[mt][1] = __builtin_amdgcn_mfma_f32_16x16x32_bf16(af, bf1, acc[mt][1], 0, 0, 0);
                }
            }
        }
        #pragma unroll
        for (int mt = 0; mt < 4; ++mt) {
            #pragma unroll
            for (int r = 0; r < 4; ++r) {
                int p = (w * 4 + mt) * 16 + (lg * 4 + r);
                sm.net_out[p * 27 + lr] = f2bf16(acc[mt][0][r]);
                if (lr < 9) sm.net_out[p * 27 + 16 + lr] = f2bf16(acc[mt][1][r]);
            }
        }
    }
    __syncthreads();

    // ---- P3: spline on ONE wave (all 64 active px); others pass-through ----
    const int sw   = (blockIdx.x + blockIdx.y + blockIdx.z) & 3;  // spline wave
    const int role = (w - sw) & 3;                                // 0 = active
    const int oi = 2 * (l >> 3) + (role >> 1);
    const int oj = 2 * (l & 7)  + (role & 1);
    const int gi = gi0 + oi, gj = gj0 + oj;
    const float xv = xs[oi + 2][oj + 2];
    float fx;

    if (role == 0) {
        const int p = oi * 16 + oj;
        float no[25];
        #pragma unroll
        for (int ch = 0; ch < 25; ++ch) no[ch] = bf162f(sm.net_out[p * 27 + ch]);

        float kx[9], ky[9], sa[9];
        {
            float mx = no[0];
            #pragma unroll
            for (int k = 1; k < 8; ++k) mx = fmaxf(mx, no[k]);
            float ev[8]; float sum = 0.f;
            #pragma unroll
            for (int k = 0; k < 8; ++k) { ev[k] = __expf(no[k] - mx); sum += ev[k]; }
            float inv = TWO_PI / sum;
            float run = 0.f;
            kx[0] = 0.f;
            #pragma unroll
            for (int k = 0; k < 8; ++k) { run += ev[k]; kx[k + 1] = run * inv; }
            kx[8] = TWO_PI;
        }
        {
            float mx = no[8];
            #pragma unroll
            for (int k = 1; k < 8; ++k) mx = fmaxf(mx, no[8 + k]);
            float ev[8]; float sum = 0.f;
            #pragma unroll
            for (int k = 0; k < 8; ++k) { ev[k] = __expf(no[8 + k] - mx); sum += ev[k]; }
            float inv = TWO_PI / sum;
            float run = 0.f;
            ky[0] = 0.f;
            #pragma unroll
            for (int k = 0; k < 8; ++k) { run += ev[k]; ky[k + 1] = run * inv; }
            ky[8] = TWO_PI;
        }
        #pragma unroll
        for (int k = 0; k < 8; ++k) {
            float v = no[16 + k];
            sa[k] = (v > 20.f) ? v : __logf(1.0f + __expf(v));
        }
        sa[8] = sa[0];

        float x1 = fmodf(xv, TWO_PI);
        if (x1 < 0.f) x1 += TWO_PI;

        int idx = 0;
        #pragma unroll
        for (int k = 1; k < 8; ++k) idx += (kx[k] <= x1) ? 1 : 0;

        float xk = 0, xk1 = 0, yk = 0, yk1 = 0, dk = 0, dk1 = 0;
        #pragma unroll
        for (int k = 0; k < 9; ++k) {
            if (k == idx)     { xk  = kx[k]; yk  = ky[k]; dk  = sa[k]; }
            if (k == idx + 1) { xk1 = kx[k]; yk1 = ky[k]; dk1 = sa[k]; }
        }

        float wk  = xk1 - xk;
        float hk  = yk1 - yk;
        float sl  = hk / wk;
        float th  = (x1 - xk) / wk;
        float th1 = th * (1.f - th);
        float den = sl + (dk1 + dk - 2.f * sl) * th1;
        float fx1 = yk + hk * (sl * th * th + dk * th1) / den;
        float omt = 1.f - th;
        float deriv = sl * sl * (dk1 * th * th + 2.f * sl * th1 + dk * omt * omt)
                      / (den * den);
        float logd = __logf(deriv);

        float t = no[24];
        float m = fmodf(fx1 + t, TWO_PI);
        if (m < 0.f) m += TWO_PI;
        fx = m;

        fx_out[(size_t)bb * 65536 + gi * 256 + gj] = fx;

        // logJ: reduce within this single wave
        #pragma unroll
        for (int off = 32; off > 0; off >>= 1)
            logd += __shfl_down(logd, off);
        if (l == 0) atomicAdd(&logj_out[bb], logd);
    } else {
        fx_out[(size_t)bb * 65536 + gi * 256 + gj] = xv;  // passive + frozen
    }
}

extern "C" void kernel_launch(void* const* d_in, const int* in_sizes, int n_in,
                              void* d_out, int out_size, void* d_ws, size_t ws_size,
                              hipStream_t stream) {
    const float* x  = (const float*)d_in[0];
    const float* w1 = (const float*)d_in[4];
    const float* b1 = (const float*)d_in[5];
    const float* w2 = (const float*)d_in[6];
    const float* b2 = (const float*)d_in[7];

    float* fx_out = (float*)d_out;
    float* logj   = (float*)d_out + (size_t)16 * 256 * 256;
    unsigned short* ws = (unsigned short*)d_ws;

    hipMemsetAsync(logj, 0, 16 * sizeof(float), stream);
    prep_weights<<<1, 256, 0, stream>>>(w1, w2, ws);

    dim3 grid(16, 16, 16);   // (j-tiles, i-tiles, batch)
    plaq_fused<<<grid, 256, 0, stream>>>(x, b1, b2, ws, fx_out, logj);
}

// Round 6
// 81.538 us; speedup vs baseline: 5.4566x; 1.0123x over previous
//
#include <hip/hip_runtime.h>
#include <hip/hip_bf16.h>

#define TWO_PI 6.283185307179586f

typedef __attribute__((ext_vector_type(8))) short short8;
typedef __attribute__((ext_vector_type(4))) float f32x4;
typedef __attribute__((ext_vector_type(4))) unsigned u32x4;

// Manual RNE bf16 conversions. NOTE (R5 post-mortem): v_cvt_pk_bf16_f32
// appears to truncate on gfx950 — the resulting -0.5ulp mean bias blew up
// the 16384-term logJ sum to absmax 44. Keep RNE; do not "optimize" these.
__device__ __forceinline__ unsigned pack2_bf16(float lo, float hi) {
    unsigned a = __float_as_uint(lo), b = __float_as_uint(hi);
    a = (a + 0x7fffu + ((a >> 16) & 1)) >> 16;
    b = (b + 0x7fffu + ((b >> 16) & 1)) & 0xffff0000u;
    return b | a;
}
__device__ __forceinline__ unsigned short f2bf16(float f) {
    unsigned a = __float_as_uint(f);
    return (unsigned short)((a + 0x7fffu + ((a >> 16) & 1)) >> 16);
}
__device__ __forceinline__ float bf162f(unsigned short h) {
    return __uint_as_float(((unsigned)h) << 16);
}
__device__ __forceinline__ float gelu_fast(float a) {
    // jax tanh-gelu == a * sigmoid(1.5957691*(a + 0.044715 a^3))
    float u = a + 0.044715f * a * a * a;
    float e = __expf(-1.5957691216057308f * u);
    return a * __builtin_amdgcn_rcpf(1.0f + e);
}

// ---- weight prep: once per launch -> d_ws (bf16) ----
// ws[0..1024)      : w1t[32 o][32 k], k = 2*tap + in  (k>=18 zero)
// ws[1024..10240)  : wt[9 q][4 cb][32 o][8 ci]        (o>=25 zero)
__global__ void prep_weights(const float* __restrict__ w1,
                             const float* __restrict__ w2,
                             unsigned short* __restrict__ ws) {
    for (int t = threadIdx.x; t < 10240; t += 256) {
        float f = 0.0f;
        if (t < 1024) {
            int o = t >> 5, k = t & 31;
            if (k < 18) f = w1[o * 18 + (k & 1) * 9 + (k >> 1)];
        } else {
            int idx = t - 1024;
            int q  = idx >> 10;
            int r  = idx & 1023;
            int cb = r >> 8;
            int o  = (r >> 3) & 31;
            int ci = r & 7;
            if (o < 25) f = w2[(o * 32 + cb * 8 + ci) * 9 + q];
        }
        ws[t] = f2bf16(f);
    }
}

// hs plane stride: 18*18*8 = 2592 shorts, padded to 2640 (plane phase = 8 banks
// mod 32 -> the 4 lg-groups of a wave are bank-disjoint on ds_read_b128).
#define HS_PS 2640
#define NO_STRIDE 28   // net_out pixel stride (words lg*56 = disjoint phases)

// B=16, L=256, hidden=32, n_bins=8, n_out=25. Tile 16x16, 256 threads (4 waves).
__global__ __launch_bounds__(256, 4) void plaq_fused(
    const float* __restrict__ x,
    const float* __restrict__ b1, const float* __restrict__ b2,
    const unsigned short* __restrict__ ws,
    float* __restrict__ fx_out, float* __restrict__ logj_out)
{
    const int tid = threadIdx.x;
    const int bb  = blockIdx.z;
    const int gi0 = blockIdx.y * 16;
    const int gj0 = blockIdx.x * 16;

    __shared__ float xs[20][20];                         // 1600 B
    __shared__ __align__(16) union {
        unsigned cssn[401];                    // packed (cos,sin) bf16; [400]=0
        unsigned short net_out[256 * NO_STRIDE];  // conv2 out bf16 (14336 B)
    } sm;
    __shared__ __align__(16) unsigned short hs[4 * HS_PS]; // gelu(conv1) (21120 B)

    const float* xb = x + (size_t)bb * 65536;

    // ---- P0: stage x tile + packed cos/sin ----
    for (int t = tid; t < 400; t += 256) {
        int r = t / 20, c = t % 20;
        int gr = (gi0 + r - 2) & 255, gc = (gj0 + c - 2) & 255;
        float v = xb[gr * 256 + gc];
        xs[r][c] = v;
        unsigned pk;
        if ((gr ^ gc) & 1) { float sn, cs; __sincosf(v, &sn, &cs); pk = pack2_bf16(cs, sn); }
        else               { pk = 0x3f80u; }   // (cos,sin)=(1,0)
        sm.cssn[t] = pk;
    }
    if (tid == 0) sm.cssn[400] = 0;
    __syncthreads();

    const int w  = tid >> 6;
    const int l  = tid & 63;
    const int lg = l >> 4;        // k-slice group
    const int lr = l & 15;        // A-row / B-col within 16x16 tile

    // ---- P1: conv1 via MFMA (M=324, N=32, K=18 in K=32 slot) + GELU -> hs ----
    {
        short8 bf0 = *(const short8*)(ws + (lr * 32 + lg * 8));
        short8 bf1 = *(const short8*)(ws + ((16 + lr) * 32 + lg * 8));
        const float bias0 = b1[lr], bias1 = b1[16 + lr];

        // per-lane tap offsets (taps 4lg .. 4lg+3; tap>8 -> zero word @400)
        int offv[4]; bool valv[4];
        #pragma unroll
        for (int i = 0; i < 4; ++i) {
            int tap = lg * 4 + i;
            valv[i] = (tap <= 8);
            int di = tap / 3, dj = tap - di * 3;
            offv[i] = di * 20 + dj;
        }

        unsigned short* hp0 = &hs[(lr >> 3) * HS_PS + (lr & 7)];
        unsigned short* hp1 = &hs[(2 + (lr >> 3)) * HS_PS + (lr & 7)];

        for (int mt = w; mt < 21; mt += 4) {
            int p  = mt * 16 + lr;
            int hi = p / 18, hj = p - hi * 18;
            int base = hi * 20 + hj;
            u32x4 aw;
            #pragma unroll
            for (int i = 0; i < 4; ++i)
                aw[i] = sm.cssn[valv[i] ? base + offv[i] : 400];
            short8 af = __builtin_bit_cast(short8, aw);

            f32x4 d0 = (f32x4){bias0, bias0, bias0, bias0};
            f32x4 d1 = (f32x4){bias1, bias1, bias1, bias1};
            d0 = __builtin_amdgcn_mfma_f32_16x16x32_bf16(af, bf0, d0, 0, 0, 0);
            d1 = __builtin_amdgcn_mfma_f32_16x16x32_bf16(af, bf1, d1, 0, 0, 0);

            #pragma unroll
            for (int r = 0; r < 4; ++r) {
                int pp = mt * 16 + lg * 4 + r;
                if (pp < 324) {
                    hp0[pp * 8] = f2bf16(gelu_fast(d0[r]));
                    hp1[pp * 8] = f2bf16(gelu_fast(d1[r]));
                }
            }
        }
    }
    __syncthreads();

    // ---- P2: conv2 via MFMA (implicit GEMM, K-step = one tap) ----
    {
        const unsigned short* wt = ws + 1024;   // [9][4][32][8]
        float bv0 = b2[lr];
        float bv1 = (lr < 9) ? b2[16 + lr] : 0.0f;
        f32x4 acc[4][2];
        #pragma unroll
        for (int mt = 0; mt < 4; ++mt) {
            acc[mt][0] = (f32x4){bv0, bv0, bv0, bv0};
            acc[mt][1] = (f32x4){bv1, bv1, bv1, bv1};
        }
        #pragma unroll
        for (int di = 0; di < 3; ++di) {
            #pragma unroll
            for (int dj = 0; dj < 3; ++dj) {
                int q = di * 3 + dj;
                short8 bf0 = *(const short8*)(wt + ((q * 4 + lg) * 32 + lr) * 8);
                short8 bf1 = *(const short8*)(wt + ((q * 4 + lg) * 32 + 16 + lr) * 8);
                #pragma unroll
                for (int mt = 0; mt < 4; ++mt) {
                    const unsigned short* ap =
                        &hs[lg * HS_PS + ((w * 4 + mt + di) * 18 + lr + dj) * 8];
                    short8 af = *(const short8*)ap;
                    acc[mt][0] = __builtin_amdgcn_mfma_f32_16x16x32_bf16(af, bf0, acc[mt][0], 0, 0, 0);
                    acc[mt][1] = __builtin_amdgcn_mfma_f32_16x16x32_bf16(af, bf1, acc[mt][1], 0, 0, 0);
                }
            }
        }
        #pragma unroll
        for (int mt = 0; mt < 4; ++mt) {
            #pragma unroll
            for (int r = 0; r < 4; ++r) {
                int p = (w * 4 + mt) * 16 + (lg * 4 + r);
                sm.net_out[p * NO_STRIDE + lr] = f2bf16(acc[mt][0][r]);
                if (lr < 9) sm.net_out[p * NO_STRIDE + 16 + lr] = f2bf16(acc[mt][1][r]);
            }
        }
    }
    __syncthreads();

    // ---- P3: spline on ONE wave (all 64 active px); others pass-through ----
    const int sw   = (blockIdx.x + blockIdx.y + blockIdx.z) & 3;  // spline wave
    const int role = (w - sw) & 3;                                // 0 = active
    const int oi = 2 * (l >> 3) + (role >> 1);
    const int oj = 2 * (l & 7)  + (role & 1);
    const int gi = gi0 + oi, gj = gj0 + oj;
    const float xv = xs[oi + 2][oj + 2];

    if (role == 0) {
        const int p = oi * 16 + oj;
        float no[25];
        #pragma unroll
        for (int ch = 0; ch < 25; ++ch) no[ch] = bf162f(sm.net_out[p * NO_STRIDE + ch]);

        float kx[9], ky[9], sa[9];
        {
            float mx = no[0];
            #pragma unroll
            for (int k = 1; k < 8; ++k) mx = fmaxf(mx, no[k]);
            float ev[8]; float sum = 0.f;
            #pragma unroll
            for (int k = 0; k < 8; ++k) { ev[k] = __expf(no[k] - mx); sum += ev[k]; }
            float inv = TWO_PI / sum;
            float run = 0.f;
            kx[0] = 0.f;
            #pragma unroll
            for (int k = 0; k < 8; ++k) { run += ev[k]; kx[k + 1] = run * inv; }
            kx[8] = TWO_PI;
        }
        {
            float mx = no[8];
            #pragma unroll
            for (int k = 1; k < 8; ++k) mx = fmaxf(mx, no[8 + k]);
            float ev[8]; float sum = 0.f;
            #pragma unroll
            for (int k = 0; k < 8; ++k) { ev[k] = __expf(no[8 + k] - mx); sum += ev[k]; }
            float inv = TWO_PI / sum;
            float run = 0.f;
            ky[0] = 0.f;
            #pragma unroll
            for (int k = 0; k < 8; ++k) { run += ev[k]; ky[k + 1] = run * inv; }
            ky[8] = TWO_PI;
        }
        #pragma unroll
        for (int k = 0; k < 8; ++k) {
            float v = no[16 + k];
            sa[k] = (v > 20.f) ? v : __logf(1.0f + __expf(v));
        }
        sa[8] = sa[0];

        float x1 = fmodf(xv, TWO_PI);
        if (x1 < 0.f) x1 += TWO_PI;

        int idx = 0;
        #pragma unroll
        for (int k = 1; k < 8; ++k) idx += (kx[k] <= x1) ? 1 : 0;

        float xk = 0, xk1 = 0, yk = 0, yk1 = 0, dk = 0, dk1 = 0;
        #pragma unroll
        for (int k = 0; k < 9; ++k) {
            if (k == idx)     { xk  = kx[k]; yk  = ky[k]; dk  = sa[k]; }
            if (k == idx + 1) { xk1 = kx[k]; yk1 = ky[k]; dk1 = sa[k]; }
        }

        float wk  = xk1 - xk;
        float hk  = yk1 - yk;
        float sl  = hk / wk;
        float th  = (x1 - xk) / wk;
        float th1 = th * (1.f - th);
        float den = sl + (dk1 + dk - 2.f * sl) * th1;
        float fx1 = yk + hk * (sl * th * th + dk * th1) / den;
        float omt = 1.f - th;
        float deriv = sl * sl * (dk1 * th * th + 2.f * sl * th1 + dk * omt * omt)
                      / (den * den);
        float logd = __logf(deriv);

        float t = no[24];
        float m = fmodf(fx1 + t, TWO_PI);
        if (m < 0.f) m += TWO_PI;

        fx_out[(size_t)bb * 65536 + gi * 256 + gj] = m;

        // logJ: reduce within this single wave
        #pragma unroll
        for (int off = 32; off > 0; off >>= 1)
            logd += __shfl_down(logd, off);
        if (l == 0) atomicAdd(&logj_out[bb], logd);
    } else {
        fx_out[(size_t)bb * 65536 + gi * 256 + gj] = xv;  // passive + frozen
    }
}

extern "C" void kernel_launch(void* const* d_in, const int* in_sizes, int n_in,
                              void* d_out, int out_size, void* d_ws, size_t ws_size,
                              hipStream_t stream) {
    const float* x  = (const float*)d_in[0];
    const float* w1 = (const float*)d_in[4];
    const float* b1 = (const float*)d_in[5];
    const float* w2 = (const float*)d_in[6];
    const float* b2 = (const float*)d_in[7];

    float* fx_out = (float*)d_out;
    float* logj   = (float*)d_out + (size_t)16 * 256 * 256;
    unsigned short* ws = (unsigned short*)d_ws;

    hipMemsetAsync(logj, 0, 16 * sizeof(float), stream);
    prep_weights<<<1, 256, 0, stream>>>(w1, w2, ws);

    dim3 grid(16, 16, 16);   // (j-tiles, i-tiles, batch)
    plaq_fused<<<grid, 256, 0, stream>>>(x, b1, b2, ws, fx_out, logj);
}

// Round 7
// 79.682 us; speedup vs baseline: 5.5837x; 1.0233x over previous
//
#include <hip/hip_runtime.h>
#include <hip/hip_bf16.h>

#define TWO_PI 6.283185307179586f

typedef __attribute__((ext_vector_type(8))) short short8;
typedef __attribute__((ext_vector_type(4))) float f32x4;
typedef __attribute__((ext_vector_type(4))) unsigned u32x4;

// Manual RNE bf16 conversions. NOTE (R5 post-mortem): v_cvt_pk_bf16_f32
// truncates on gfx950 — its -0.5ulp mean bias blew the 16384-term logJ
// sum to absmax 44. Keep RNE; do not "optimize" these.
__device__ __forceinline__ unsigned pack2_bf16(float lo, float hi) {
    unsigned a = __float_as_uint(lo), b = __float_as_uint(hi);
    a = (a + 0x7fffu + ((a >> 16) & 1)) >> 16;
    b = (b + 0x7fffu + ((b >> 16) & 1)) & 0xffff0000u;
    return b | a;
}
__device__ __forceinline__ unsigned short f2bf16(float f) {
    unsigned a = __float_as_uint(f);
    return (unsigned short)((a + 0x7fffu + ((a >> 16) & 1)) >> 16);
}
__device__ __forceinline__ float bf162f(unsigned short h) {
    return __uint_as_float(((unsigned)h) << 16);
}
__device__ __forceinline__ float gelu_fast(float a) {
    // jax tanh-gelu == a * sigmoid(1.5957691*(a + 0.044715 a^3))
    float u = a + 0.044715f * a * a * a;
    float e = __expf(-1.5957691216057308f * u);
    return a * __builtin_amdgcn_rcpf(1.0f + e);
}

// ---- weight prep: once per launch -> d_ws (bf16) ----
// ws[0..1024)      : w1t[32 o][32 k]; column o<16 -> channel 2o, o>=16 ->
//                    channel 2(o-16)+1 (pairing for P1's packed store);
//                    k = 2*tap + in (k>=18 zero)
// ws[1024..10240)  : wt[9 q][4 cb][32 o][8 ci]  (o>=25 zero), ch = 8cb+ci
__global__ void prep_weights(const float* __restrict__ w1,
                             const float* __restrict__ w2,
                             unsigned short* __restrict__ ws) {
    for (int t = threadIdx.x; t < 10240; t += 256) {
        float f = 0.0f;
        if (t < 1024) {
            int o = t >> 5, k = t & 31;
            int ch = (o < 16) ? 2 * o : 2 * (o - 16) + 1;
            if (k < 18) f = w1[ch * 18 + (k & 1) * 9 + (k >> 1)];
        } else {
            int idx = t - 1024;
            int q  = idx >> 10;
            int r  = idx & 1023;
            int cb = r >> 8;
            int o  = (r >> 3) & 31;
            int ci = r & 7;
            if (o < 25) f = w2[(o * 32 + cb * 8 + ci) * 9 + q];
        }
        ws[t] = f2bf16(f);
    }
}

#define NO2 30   // net_out pixel stride in shorts (15 words: odd bank walk)

// B=16, L=256, hidden=32, n_bins=8, n_out=25. Tile 16x16, 256 threads.
// conv2 computed ONLY at the 64 active (even,even) pixels per tile.
__global__ __launch_bounds__(256, 5) void plaq_fused(
    const float* __restrict__ x,
    const float* __restrict__ b1, const float* __restrict__ b2,
    const unsigned short* __restrict__ ws,
    float* __restrict__ fx_out, float* __restrict__ logj_out)
{
    const int tid = threadIdx.x;
    const int bb  = blockIdx.z;
    const int gi0 = blockIdx.y * 16;
    const int gj0 = blockIdx.x * 16;

    __shared__ float xs[20][20];                    // pixel (r-2, c-2); 1600 B
    __shared__ __align__(16) union {
        unsigned cssn[400];                         // packed (cos,sin) bf16
        unsigned short net_out[64 * NO2];           // conv2 @ active px (3840 B)
    } sm;
    // h (gelu of conv1) at positions pos = hpi*17+hpj, pixel (hpi-1, hpj-1),
    // pos in [0,289). Layout: 16B slot = 8 channels; slot = pos*4 + (ch>>3),
    // XOR-swizzled: slot ^= (slot>>3)&7 (involution, used by writer+reader).
    __shared__ __align__(16) unsigned hs_u32[4640]; // 1160 slots (18560 B)

    const float* xb = x + (size_t)bb * 65536;

    // ---- P0: stage x tile + packed cos/sin ----
    for (int t = tid; t < 400; t += 256) {
        int r = t / 20, c = t % 20;
        int gr = (gi0 + r - 2) & 255, gc = (gj0 + c - 2) & 255;
        float v = xb[gr * 256 + gc];
        xs[r][c] = v;
        unsigned pk;
        if ((gr ^ gc) & 1) { float sn, cs; __sincosf(v, &sn, &cs); pk = pack2_bf16(cs, sn); }
        else               { pk = 0x3f80u; }   // (cos,sin)=(1,0)
        sm.cssn[t] = pk;
    }
    __syncthreads();

    const int w  = tid >> 6;
    const int l  = tid & 63;
    const int lg = l >> 4;        // k-slice group
    const int lr = l & 15;        // A-row / B-col within 16x16 MFMA tile

    // ---- P1: conv1 via MFMA (M=289 pos, N=32 ch, K=18) + GELU -> hs ----
    {
        short8 bf0 = *(const short8*)(ws + (lr * 32 + lg * 8));        // ch 2lr
        short8 bf1 = *(const short8*)(ws + ((16 + lr) * 32 + lg * 8)); // ch 2lr+1
        const float bias0 = b1[2 * lr], bias1 = b1[2 * lr + 1];

        int offv[4];
        #pragma unroll
        for (int i = 0; i < 4; ++i) {
            int t = lg * 4 + i;
            // taps >8 have zero weights; any in-range addr is fine (finite*0=0)
            offv[i] = (t <= 8) ? (t / 3) * 20 + t - (t / 3) * 3 : 0;
        }

        #pragma unroll
        for (int it = 0; it < 5; ++it) {
            int mt = w + 4 * it;
            if (mt < 19) {
                int pr  = mt * 16 + lr;              // position this lane reads
                int hpi = pr / 17, hpj = pr - hpi * 17;
                int base = hpi * 20 + hpj;
                u32x4 aw;
                #pragma unroll
                for (int i = 0; i < 4; ++i) aw[i] = sm.cssn[base + offv[i]];
                short8 af = __builtin_bit_cast(short8, aw);

                f32x4 d0 = (f32x4){bias0, bias0, bias0, bias0};
                f32x4 d1 = (f32x4){bias1, bias1, bias1, bias1};
                d0 = __builtin_amdgcn_mfma_f32_16x16x32_bf16(af, bf0, d0, 0, 0, 0);
                d1 = __builtin_amdgcn_mfma_f32_16x16x32_bf16(af, bf1, d1, 0, 0, 0);

                #pragma unroll
                for (int r = 0; r < 4; ++r) {
                    int ps = mt * 16 + 4 * lg + r;   // position this lane stores
                    if (ps < 289) {
                        unsigned pk = pack2_bf16(gelu_fast(d0[r]), gelu_fast(d1[r]));
                        int slot = ps * 4 + (lr >> 2);
                        slot ^= (slot >> 3) & 7;
                        hs_u32[slot * 4 + (lr & 3)] = pk;
                    }
                }
            }
        }
    }
    __syncthreads();

    // ---- P2: conv2 via MFMA at ACTIVE pixels only (M=64, N=25, K=288) ----
    {
        const unsigned short* wt = ws + 1024;   // [9][4][32][8]
        const int a  = 16 * w + lr;             // active-pixel index this lane reads
        const int ai = a >> 3, aj = a & 7;      // active px = (2ai, 2aj)
        float bv0 = b2[lr];
        float bv1 = (lr < 9) ? b2[16 + lr] : 0.0f;
        f32x4 acc0 = (f32x4){bv0, bv0, bv0, bv0};
        f32x4 acc1 = (f32x4){bv1, bv1, bv1, bv1};

        #pragma unroll
        for (int di = 0; di < 3; ++di) {
            #pragma unroll
            for (int dj = 0; dj < 3; ++dj) {
                int q = di * 3 + dj;
                short8 b0 = *(const short8*)(wt + ((q * 4 + lg) * 32 + lr) * 8);
                short8 b1v = *(const short8*)(wt + ((q * 4 + lg) * 32 + 16 + lr) * 8);
                int pos  = (2 * ai + di) * 17 + 2 * aj + dj;
                int slot = pos * 4 + lg;
                slot ^= (slot >> 3) & 7;
                short8 af = *(const short8*)&hs_u32[slot * 4];
                acc0 = __builtin_amdgcn_mfma_f32_16x16x32_bf16(af, b0, acc0, 0, 0, 0);
                acc1 = __builtin_amdgcn_mfma_f32_16x16x32_bf16(af, b1v, acc1, 0, 0, 0);
            }
        }
        #pragma unroll
        for (int r = 0; r < 4; ++r) {
            int p = 16 * w + 4 * lg + r;        // active-pixel index stored
            sm.net_out[p * NO2 + lr] = f2bf16(acc0[r]);
            if (lr < 9) sm.net_out[p * NO2 + 16 + lr] = f2bf16(acc1[r]);
        }
    }
    __syncthreads();

    // ---- P3: spline on ONE wave (64 active px); others pass-through ----
    const int sw   = (blockIdx.x + blockIdx.y + blockIdx.z) & 3;
    const int role = (w - sw) & 3;              // 0 = spline wave
    const int oi = 2 * (l >> 3) + (role >> 1);
    const int oj = 2 * (l & 7)  + (role & 1);
    const int gi = gi0 + oi, gj = gj0 + oj;
    const float xv = xs[oi + 2][oj + 2];

    if (role == 0) {
        float no[25];
        #pragma unroll
        for (int ch = 0; ch < 25; ++ch) no[ch] = bf162f(sm.net_out[l * NO2 + ch]);

        float kx[9], ky[9], sa[9];
        {
            float mx = no[0];
            #pragma unroll
            for (int k = 1; k < 8; ++k) mx = fmaxf(mx, no[k]);
            float ev[8]; float sum = 0.f;
            #pragma unroll
            for (int k = 0; k < 8; ++k) { ev[k] = __expf(no[k] - mx); sum += ev[k]; }
            float inv = TWO_PI / sum;
            float run = 0.f;
            kx[0] = 0.f;
            #pragma unroll
            for (int k = 0; k < 8; ++k) { run += ev[k]; kx[k + 1] = run * inv; }
            kx[8] = TWO_PI;
        }
        {
            float mx = no[8];
            #pragma unroll
            for (int k = 1; k < 8; ++k) mx = fmaxf(mx, no[8 + k]);
            float ev[8]; float sum = 0.f;
            #pragma unroll
            for (int k = 0; k < 8; ++k) { ev[k] = __expf(no[8 + k] - mx); sum += ev[k]; }
            float inv = TWO_PI / sum;
            float run = 0.f;
            ky[0] = 0.f;
            #pragma unroll
            for (int k = 0; k < 8; ++k) { run += ev[k]; ky[k + 1] = run * inv; }
            ky[8] = TWO_PI;
        }
        #pragma unroll
        for (int k = 0; k < 8; ++k) {
            float v = no[16 + k];
            sa[k] = (v > 20.f) ? v : __logf(1.0f + __expf(v));
        }
        sa[8] = sa[0];

        // x in [0, 2pi) by construction -> mod is identity
        float x1 = xv;

        int idx = 0;
        #pragma unroll
        for (int k = 1; k < 8; ++k) idx += (kx[k] <= x1) ? 1 : 0;

        float xk = 0, xk1 = 0, yk = 0, yk1 = 0, dk = 0, dk1 = 0;
        #pragma unroll
        for (int k = 0; k < 9; ++k) {
            if (k == idx)     { xk  = kx[k]; yk  = ky[k]; dk  = sa[k]; }
            if (k == idx + 1) { xk1 = kx[k]; yk1 = ky[k]; dk1 = sa[k]; }
        }

        float wk  = xk1 - xk;
        float hk  = yk1 - yk;
        float sl  = hk / wk;
        float th  = (x1 - xk) / wk;
        float th1 = th * (1.f - th);
        float den = sl + (dk1 + dk - 2.f * sl) * th1;
        float fx1 = yk + hk * (sl * th * th + dk * th1) / den;
        float omt = 1.f - th;
        float deriv = sl * sl * (dk1 * th * th + 2.f * sl * th1 + dk * omt * omt)
                      / (den * den);
        float logd = __logf(deriv);

        // |t| << 2pi (18-sigma bound) -> single-step wrap each side
        float m = fx1 + no[24];
        if (m >= TWO_PI) m -= TWO_PI;
        if (m < 0.f)     m += TWO_PI;

        fx_out[(size_t)bb * 65536 + gi * 256 + gj] = m;

        #pragma unroll
        for (int off = 32; off > 0; off >>= 1)
            logd += __shfl_down(logd, off);
        if (l == 0) atomicAdd(&logj_out[bb], logd);
    } else {
        fx_out[(size_t)bb * 65536 + gi * 256 + gj] = xv;  // passive + frozen
    }
}

extern "C" void kernel_launch(void* const* d_in, const int* in_sizes, int n_in,
                              void* d_out, int out_size, void* d_ws, size_t ws_size,
                              hipStream_t stream) {
    const float* x  = (const float*)d_in[0];
    const float* w1 = (const float*)d_in[4];
    const float* b1 = (const float*)d_in[5];
    const float* w2 = (const float*)d_in[6];
    const float* b2 = (const float*)d_in[7];

    float* fx_out = (float*)d_out;
    float* logj   = (float*)d_out + (size_t)16 * 256 * 256;
    unsigned short* ws = (unsigned short*)d_ws;

    hipMemsetAsync(logj, 0, 16 * sizeof(float), stream);
    prep_weights<<<1, 256, 0, stream>>>(w1, w2, ws);

    dim3 grid(16, 16, 16);   // (j-tiles, i-tiles, batch)
    plaq_fused<<<grid, 256, 0, stream>>>(x, b1, b2, ws, fx_out, logj);
}

// Round 8
// 73.442 us; speedup vs baseline: 6.0581x; 1.0850x over previous
//
#include <hip/hip_runtime.h>
#include <hip/hip_bf16.h>

#define TWO_PI 6.283185307179586f

typedef __attribute__((ext_vector_type(8))) short short8;
typedef __attribute__((ext_vector_type(4))) float f32x4;
typedef __attribute__((ext_vector_type(4))) unsigned u32x4;

// Manual RNE bf16 conversions. NOTE (R5 post-mortem): v_cvt_pk_bf16_f32
// truncates on gfx950 — its -0.5ulp mean bias blew the 16384-term logJ
// sum to absmax 44. Keep RNE; do not "optimize" these.
__device__ __forceinline__ unsigned pack2_bf16(float lo, float hi) {
    unsigned a = __float_as_uint(lo), b = __float_as_uint(hi);
    a = (a + 0x7fffu + ((a >> 16) & 1)) >> 16;
    b = (b + 0x7fffu + ((b >> 16) & 1)) & 0xffff0000u;
    return b | a;
}
__device__ __forceinline__ unsigned short f2bf16(float f) {
    unsigned a = __float_as_uint(f);
    return (unsigned short)((a + 0x7fffu + ((a >> 16) & 1)) >> 16);
}
__device__ __forceinline__ float bf162f(unsigned short h) {
    return __uint_as_float(((unsigned)h) << 16);
}
__device__ __forceinline__ float gelu_fast(float a) {
    // jax tanh-gelu == a * sigmoid(1.5957691*(a + 0.044715 a^3))
    float u = a + 0.044715f * a * a * a;
    float e = __expf(-1.5957691216057308f * u);
    return a * __builtin_amdgcn_rcpf(1.0f + e);
}

// ---- weight prep (40 blocks, 1 elem/thread) + logJ zero-init ----
// ws[0..1024)      : w1t[32 o][32 k]; col o<16 -> ch 2o, o>=16 -> ch 2(o-16)+1
//                    k = 2*tap + in (k>=18 zero)
// ws[1024..10240)  : wt[9 q][4 cb][32 o][8 ci]  (o>=25 zero), ch = 8cb+ci
__global__ void prep_weights(const float* __restrict__ w1,
                             const float* __restrict__ w2,
                             unsigned short* __restrict__ ws,
                             float* __restrict__ logj) {
    int t = blockIdx.x * 256 + threadIdx.x;
    if (blockIdx.x == 0 && threadIdx.x < 16) logj[threadIdx.x] = 0.0f;
    if (t >= 10240) return;
    float f = 0.0f;
    if (t < 1024) {
        int o = t >> 5, k = t & 31;
        int ch = (o < 16) ? 2 * o : 2 * (o - 16) + 1;
        if (k < 18) f = w1[ch * 18 + (k & 1) * 9 + (k >> 1)];
    } else {
        int idx = t - 1024;
        int q  = idx >> 10;
        int r  = idx & 1023;
        int cb = r >> 8;
        int o  = (r >> 3) & 31;
        int ci = r & 7;
        if (o < 25) f = w2[(o * 32 + cb * 8 + ci) * 9 + q];
    }
    ws[t] = f2bf16(f);
}

#define NO2 30     // net_out pixel stride in shorts
#define NPOS 578   // h positions: 17 rows x 34 cols (strip 16x32 + halo 1)
#define NMT 37     // ceil(578/16) M-tiles in P1

// B=16, L=256. Block = 16x32 strip (2 tiles), 512 threads (8 waves).
// conv2 only at the 128 active (even,even) pixels of the strip.
__global__ __launch_bounds__(512, 6) void plaq_fused(
    const float* __restrict__ x,
    const float* __restrict__ b1, const float* __restrict__ b2,
    const unsigned short* __restrict__ ws,
    float* __restrict__ fx_out, float* __restrict__ logj_out)
{
    const int tid = threadIdx.x;
    const int bb  = blockIdx.z;
    const int gi0 = blockIdx.y * 16;
    const int gj0 = blockIdx.x * 32;

    __shared__ float xs[20][36];                    // pixel (r-2, c-2); 2880 B
    __shared__ __align__(16) union {
        unsigned cssn[720];                         // packed (cos,sin) bf16
        unsigned short net_out[128 * NO2];          // conv2 @ active px (7680 B)
    } sm;
    // h: pos = hpi*34 + hpj (pixel (hpi-1, hpj-1)), pos in [0,578).
    // 16B slot = 8 ch; slot = pos*4 + (ch>>3); swizzle slot ^= (slot>>3)&7.
    __shared__ __align__(16) unsigned hs_u32[NPOS * 16];   // 36992 B

    const float* xb = x + (size_t)bb * 65536;

    // ---- P0: stage x strip + packed cos/sin ----
    for (int t = tid; t < 720; t += 512) {
        int r = t / 36, c = t - (t / 36) * 36;
        int gr = (gi0 + r - 2) & 255, gc = (gj0 + c - 2) & 255;
        float v = xb[gr * 256 + gc];
        xs[r][c] = v;
        unsigned pk;
        if ((gr ^ gc) & 1) { float sn, cs; __sincosf(v, &sn, &cs); pk = pack2_bf16(cs, sn); }
        else               { pk = 0x3f80u; }   // (cos,sin)=(1,0)
        sm.cssn[t] = pk;
    }
    __syncthreads();

    const int w  = tid >> 6;      // wave 0..7
    const int l  = tid & 63;
    const int lg = l >> 4;        // k-slice group
    const int lr = l & 15;        // A-row / B-col within 16x16 MFMA tile

    // ---- P1: conv1 via MFMA (M=578 pos, N=32 ch, K=18) + GELU -> hs ----
    {
        short8 bf0 = *(const short8*)(ws + (lr * 32 + lg * 8));        // ch 2lr
        short8 bf1 = *(const short8*)(ws + ((16 + lr) * 32 + lg * 8)); // ch 2lr+1
        const float bias0 = b1[2 * lr], bias1 = b1[2 * lr + 1];

        int offv[4];
        #pragma unroll
        for (int i = 0; i < 4; ++i) {
            int t = lg * 4 + i;
            // taps >8 have zero weights; any in-range addr is fine (finite*0=0)
            offv[i] = (t <= 8) ? (t / 3) * 36 + t - (t / 3) * 3 : 0;
        }

        for (int mt = w; mt < NMT; mt += 8) {
            int pr  = mt * 16 + lr;              // position this lane reads
            int hpi = pr / 34, hpj = pr - hpi * 34;
            int base = hpi * 36 + hpj;
            u32x4 aw;
            #pragma unroll
            for (int i = 0; i < 4; ++i) aw[i] = sm.cssn[base + offv[i]];
            short8 af = __builtin_bit_cast(short8, aw);

            f32x4 d0 = (f32x4){bias0, bias0, bias0, bias0};
            f32x4 d1 = (f32x4){bias1, bias1, bias1, bias1};
            d0 = __builtin_amdgcn_mfma_f32_16x16x32_bf16(af, bf0, d0, 0, 0, 0);
            d1 = __builtin_amdgcn_mfma_f32_16x16x32_bf16(af, bf1, d1, 0, 0, 0);

            #pragma unroll
            for (int r = 0; r < 4; ++r) {
                int ps = mt * 16 + 4 * lg + r;   // position this lane stores
                if (ps < NPOS) {
                    unsigned pk = pack2_bf16(gelu_fast(d0[r]), gelu_fast(d1[r]));
                    int slot = ps * 4 + (lr >> 2);
                    slot ^= (slot >> 3) & 7;
                    hs_u32[slot * 4 + (lr & 3)] = pk;
                }
            }
        }
    }
    __syncthreads();

    // ---- P2: conv2 via MFMA at ACTIVE pixels only (M=128, N=25, K=288) ----
    {
        const unsigned short* wt = ws + 1024;   // [9][4][32][8]
        const int a  = 16 * w + lr;             // active-pixel index this lane reads
        const int ai = a >> 4, aj = a & 15;     // active px = (2ai, 2aj)
        float bv0 = b2[lr];
        float bv1 = (lr < 9) ? b2[16 + lr] : 0.0f;
        f32x4 acc0 = (f32x4){bv0, bv0, bv0, bv0};
        f32x4 acc1 = (f32x4){bv1, bv1, bv1, bv1};

        #pragma unroll
        for (int di = 0; di < 3; ++di) {
            #pragma unroll
            for (int dj = 0; dj < 3; ++dj) {
                int q = di * 3 + dj;
                short8 b0  = *(const short8*)(wt + ((q * 4 + lg) * 32 + lr) * 8);
                short8 b1v = *(const short8*)(wt + ((q * 4 + lg) * 32 + 16 + lr) * 8);
                int pos  = (2 * ai + di) * 34 + 2 * aj + dj;
                int slot = pos * 4 + lg;
                slot ^= (slot >> 3) & 7;
                short8 af = *(const short8*)&hs_u32[slot * 4];
                acc0 = __builtin_amdgcn_mfma_f32_16x16x32_bf16(af, b0,  acc0, 0, 0, 0);
                acc1 = __builtin_amdgcn_mfma_f32_16x16x32_bf16(af, b1v, acc1, 0, 0, 0);
            }
        }
        #pragma unroll
        for (int r = 0; r < 4; ++r) {
            int p = 16 * w + 4 * lg + r;        // active-pixel index stored
            sm.net_out[p * NO2 + lr] = f2bf16(acc0[r]);
            if (lr < 9) sm.net_out[p * NO2 + 16 + lr] = f2bf16(acc1[r]);
        }
    }
    __syncthreads();

    // ---- P3: spline on TWO waves (128 active px); 6 waves pass-through ----
    const int sw   = (blockIdx.x + blockIdx.y + blockIdx.z) & 7;
    const int role = (w - sw) & 7;              // 0,1 = spline waves

    if (role < 2) {
        const int a  = role * 64 + l;           // active idx 0..127
        const int oi = 2 * (a >> 4), oj = 2 * (a & 15);
        const int gi = gi0 + oi, gj = gj0 + oj;
        const float xv = xs[oi + 2][oj + 2];

        float no[25];
        #pragma unroll
        for (int ch = 0; ch < 25; ++ch) no[ch] = bf162f(sm.net_out[a * NO2 + ch]);

        float kx[9], ky[9], sa[9];
        {
            float mx = no[0];
            #pragma unroll
            for (int k = 1; k < 8; ++k) mx = fmaxf(mx, no[k]);
            float ev[8]; float sum = 0.f;
            #pragma unroll
            for (int k = 0; k < 8; ++k) { ev[k] = __expf(no[k] - mx); sum += ev[k]; }
            float inv = TWO_PI / sum;
            float run = 0.f;
            kx[0] = 0.f;
            #pragma unroll
            for (int k = 0; k < 8; ++k) { run += ev[k]; kx[k + 1] = run * inv; }
            kx[8] = TWO_PI;
        }
        {
            float mx = no[8];
            #pragma unroll
            for (int k = 1; k < 8; ++k) mx = fmaxf(mx, no[8 + k]);
            float ev[8]; float sum = 0.f;
            #pragma unroll
            for (int k = 0; k < 8; ++k) { ev[k] = __expf(no[8 + k] - mx); sum += ev[k]; }
            float inv = TWO_PI / sum;
            float run = 0.f;
            ky[0] = 0.f;
            #pragma unroll
            for (int k = 0; k < 8; ++k) { run += ev[k]; ky[k + 1] = run * inv; }
            ky[8] = TWO_PI;
        }
        #pragma unroll
        for (int k = 0; k < 8; ++k) {
            float v = no[16 + k];
            sa[k] = (v > 20.f) ? v : __logf(1.0f + __expf(v));
        }
        sa[8] = sa[0];

        // x in [0, 2pi) by construction -> mod is identity
        float x1 = xv;

        int idx = 0;
        #pragma unroll
        for (int k = 1; k < 8; ++k) idx += (kx[k] <= x1) ? 1 : 0;

        float xk = 0, xk1 = 0, yk = 0, yk1 = 0, dk = 0, dk1 = 0;
        #pragma unroll
        for (int k = 0; k < 9; ++k) {
            if (k == idx)     { xk  = kx[k]; yk  = ky[k]; dk  = sa[k]; }
            if (k == idx + 1) { xk1 = kx[k]; yk1 = ky[k]; dk1 = sa[k]; }
        }

        float wk  = xk1 - xk;
        float hk  = yk1 - yk;
        float sl  = hk / wk;
        float th  = (x1 - xk) / wk;
        float th1 = th * (1.f - th);
        float den = sl + (dk1 + dk - 2.f * sl) * th1;
        float fx1 = yk + hk * (sl * th * th + dk * th1) / den;
        float omt = 1.f - th;
        float deriv = sl * sl * (dk1 * th * th + 2.f * sl * th1 + dk * omt * omt)
                      / (den * den);
        float logd = __logf(deriv);

        // |t| << 2pi (18-sigma bound) -> single-step wrap each side
        float m = fx1 + no[24];
        if (m >= TWO_PI) m -= TWO_PI;
        if (m < 0.f)     m += TWO_PI;

        fx_out[(size_t)bb * 65536 + gi * 256 + gj] = m;

        #pragma unroll
        for (int off = 32; off > 0; off >>= 1)
            logd += __shfl_down(logd, off);
        if (l == 0) atomicAdd(&logj_out[bb], logd);
    } else {
        // pass-through: 3 offsets x 128 cells, 2 waves per offset
        const int idx3   = role - 2;            // 0..5
        const int off_id = idx3 >> 1;           // 0,1,2
        const int sub    = ((idx3 & 1) << 6) + l;   // 0..127
        const int ci = sub >> 4, cj = sub & 15;
        const int dio[3] = {0, 1, 1}, djo[3] = {1, 0, 1};
        const int oi = 2 * ci + dio[off_id];
        const int oj = 2 * cj + djo[off_id];
        const int gi = gi0 + oi, gj = gj0 + oj;
        fx_out[(size_t)bb * 65536 + gi * 256 + gj] = xs[oi + 2][oj + 2];
    }
}

extern "C" void kernel_launch(void* const* d_in, const int* in_sizes, int n_in,
                              void* d_out, int out_size, void* d_ws, size_t ws_size,
                              hipStream_t stream) {
    const float* x  = (const float*)d_in[0];
    const float* w1 = (const float*)d_in[4];
    const float* b1 = (const float*)d_in[5];
    const float* w2 = (const float*)d_in[6];
    const float* b2 = (const float*)d_in[7];

    float* fx_out = (float*)d_out;
    float* logj   = (float*)d_out + (size_t)16 * 256 * 256;
    unsigned short* ws = (unsigned short*)d_ws;

    prep_weights<<<40, 256, 0, stream>>>(w1, w2, ws, logj);

    dim3 grid(8, 16, 16);   // (j-strips of 32, i-tiles of 16, batch)
    plaq_fused<<<grid, 512, 0, stream>>>(x, b1, b2, ws, fx_out, logj);
}